// Round 14
// baseline (275.197 us; speedup 1.0000x reference)
//
#include <hip/hip_runtime.h>

#define NB_ 5      // N_BASIS
#define MD_ 5      // MAX_DELAY
#define CSL 128    // pre-neurons per coarse bucket (power of 2)
#define CAP 6144   // records per bucket (avg 5120 at E=2M,N=50k; +14 sigma)
#define CH2 8192   // edges per partition block (LDS sort tile)
#define RING 6     // i_rec ring slots (current + 5 future)

// ---------------------------------------------------------------------------
// Build: edges sorted by PRE neuron (outgoing CSR), 4-byte records.
//   record u32 = localn(7) << 24 | d(3) << 21 | eid(21)     (E=2M < 2^21)
//   rp[n] = {start, end} absolute indices into edgeRec (bucket-padded layout)
// ---------------------------------------------------------------------------

// Block-level counting sort by coarse bucket (n>>7), then STREAMING copy to
// the bucket's reserved global run — consecutive threads write consecutive
// addresses, so L2 lines fill completely (no partial-line evictions).
__global__ __launch_bounds__(256) void partition_kernel(
    const int* __restrict__ pre_idx,
    int* __restrict__ gcur,           // 512 cursors (zeroed)
    unsigned* __restrict__ part,      // NC*CAP
    int E, int N)
{
    __shared__ unsigned srt[CH2];          // 32 KB sorted records
    __shared__ unsigned short bkt[CH2];    // 16 KB bucket tag per slot
    __shared__ int hist[512];
    __shared__ int lbase[512];
    __shared__ int pos[512];
    __shared__ int gbase[512];
    __shared__ int tmp[256];

    const int t  = threadIdx.x;
    const int e0 = blockIdx.x * CH2;
    const int cnt = min(CH2, E - e0);

    hist[t] = 0; hist[t + 256] = 0;
    __syncthreads();

    // pass 1: histogram over coarse buckets
    for (int i = t; i < cnt; i += 256) {
        int pre = pre_idx[e0 + i];
        int d = pre / N;
        int n = pre - d * N;
        atomicAdd(&hist[n >> 7], 1);
    }
    __syncthreads();

    // exclusive scan of hist[0..511] (2 entries per thread)
    int a = hist[2 * t], b = hist[2 * t + 1], s = a + b;
    tmp[t] = s;
    __syncthreads();
    int x = s;
    for (int off = 1; off < 256; off <<= 1) {
        int y = (t >= off) ? tmp[t - off] : 0;
        __syncthreads();
        x += y;
        tmp[t] = x;
        __syncthreads();
    }
    int ep = x - s;
    lbase[2 * t] = ep;         pos[2 * t] = ep;
    lbase[2 * t + 1] = ep + a; pos[2 * t + 1] = ep + a;
    // reserve global runs (one atomic per non-empty bucket)
    gbase[2 * t]     = a ? atomicAdd(&gcur[2 * t], a) : 0;
    gbase[2 * t + 1] = b ? atomicAdd(&gcur[2 * t + 1], b) : 0;
    __syncthreads();

    // pass 2: scatter into LDS sorted order (pre_idx re-read is L2-hot)
    for (int i = t; i < cnt; i += 256) {
        int pre = pre_idx[e0 + i];
        int d = pre / N;
        int n = pre - d * N;
        int bk = n >> 7;
        int p = atomicAdd(&pos[bk], 1);
        srt[p] = ((unsigned)(n & (CSL - 1)) << 24) | ((unsigned)d << 21)
               | (unsigned)(e0 + i);
        bkt[p] = (unsigned short)bk;
    }
    __syncthreads();

    // pass 3: linear copy — runs of the same bucket are contiguous in both
    // LDS and global, so writes coalesce into full lines.
    for (int j = t; j < cnt; j += 256) {
        int bk = bkt[j];
        int off2 = gbase[bk] + (j - lbase[bk]);
        if (off2 < CAP)   // never triggers for uniform pre_idx (+14 sigma)
            part[(size_t)bk * CAP + off2] = srt[j];
    }
}

// one block per coarse bucket: LDS counting sort over CSL local pre-neurons.
// Also performs per-neuron parameter packing (absorbed init_kernel).
__global__ __launch_bounds__(256) void bucket_sort_kernel(
    const int* __restrict__ gcur,
    const unsigned* __restrict__ part,
    unsigned* __restrict__ edgeRec,   // NC*CAP
    uint2* __restrict__ rp,           // per-neuron {start,end}
    const float* __restrict__ decay, const float* __restrict__ cf,
    const float* __restrict__ g,     const float* __restrict__ vth,
    const float* __restrict__ vrst,  const float* __restrict__ nrm,
    const float* __restrict__ tref,  const float* __restrict__ ek,
    const float* __restrict__ am,
    float4* __restrict__ pk, float* __restrict__ v,
    int N)
{
    __shared__ int h[CSL];
    __shared__ int sc_[CSL];
    __shared__ int pos_[CSL];
    int c = blockIdx.x, t = threadIdx.x;

    // ---- absorbed init: this block packs params for its 128 neurons --------
    if (t < CSL) {
        int n = c * CSL + t;
        if (n < N) {
            pk[3 * n]     = make_float4(decay[n], cf[n], g[n], vth[n]);
            pk[3 * n + 1] = make_float4(vrst[n], nrm[n], tref[n], ek[2 * n]);
            pk[3 * n + 2] = make_float4(ek[2 * n + 1], am[2 * n], am[2 * n + 1], 0.0f);
            v[n] = vrst[n];
        }
    }

    int cnt = min(gcur[c], CAP);
    size_t base = (size_t)c * CAP;
    if (t < CSL) h[t] = 0;
    __syncthreads();
    for (int i = t; i < cnt; i += 256)
        atomicAdd(&h[part[base + i] >> 24], 1);
    __syncthreads();
    if (t < CSL) sc_[t] = h[t];
    __syncthreads();
    for (int off = 1; off < CSL; off <<= 1) {
        int y = 0;
        if (t < CSL && t >= off) y = sc_[t - off];
        __syncthreads();
        if (t < CSL && t >= off) sc_[t] += y;
        __syncthreads();
    }
    if (t < CSL) {
        int end = sc_[t];                 // inclusive end (local)
        pos_[t] = (int)base + end - h[t]; // exclusive start (absolute)
        int gn = c * CSL + t;
        if (gn < N)
            rp[gn] = make_uint2((unsigned)(base + end - h[t]),
                                (unsigned)(base + end));
    }
    __syncthreads();
    for (int i = t; i < cnt; i += 256) {
        unsigned q = part[base + i];
        int dst = atomicAdd(&pos_[q >> 24], 1);
        edgeRec[dst] = q;
    }
}

// ---------------------------------------------------------------------------
// Per-step kernel: neuron update + BLOCK-COOPERATIVE push of firing neurons'
// outgoing edges into future i_rec ring slots. One dispatch per step.
// (Byte-identical math to round 13 — bit-exact vs reference.)
// ---------------------------------------------------------------------------

__global__ __launch_bounds__(256) void step_kernel(
    const float* __restrict__ x_t,        // ext_input + t*n5
    float*       __restrict__ psc,        // n5
    const float* __restrict__ sd,         // syn_decay
    const float* __restrict__ pi,         // psc_initial
    const float4* __restrict__ pk,        // {decay,cf,g,vth}{vrst,nrm,tref,ek0}{ek1,am0,am1,_}
    float* __restrict__ v,
    float* __restrict__ r,
    float* __restrict__ asc,              // (N,2)
    float* __restrict__ ring,             // RING*n5 i_rec accumulators
    const int* __restrict__ scnt,         // scnt[MD+u] = spike count of step u
    int*       __restrict__ scnt_new,     // &scnt[MD+t]
    const float* __restrict__ out_prev,   // out + (t-1)*N (t>=1)
    float*       __restrict__ out_t,      // out + t*N
    const uint2*    __restrict__ rp,      // outgoing CSR {start,end}
    const unsigned* __restrict__ edgeRec,
    const float*    __restrict__ weights,
    const float*    __restrict__ edge_basis,
    const int*      __restrict__ post_idx,
    int t, int n5, int N)
{
    __shared__ int   nf_s;
    __shared__ uint2 rowsL[256];
    __shared__ int   scL[256];
    __shared__ int   pref[257];

    const int tloc = threadIdx.x;
    const int n = blockIdx.x * blockDim.x + tloc;
    const bool has = (n < N);
    if (tloc == 0) nf_s = 0;
    __syncthreads();

    // spike count in window t-5..t-1 (scnt offset by MD, head zeroed)
    const int* sw = scnt + t;
    int scw = sw[0] + sw[1] + sw[2] + sw[3] + sw[4];

    float z = 0.0f;
    if (has) {
        // ---- read & clear this step's i_rec ring slot (skip when quiet) ----
        float ir0 = 0.f, ir1 = 0.f, ir2 = 0.f, ir3 = 0.f, ir4 = 0.f;
        float* rg = ring + (size_t)(t % RING) * n5 + (size_t)n * NB_;
        if (scw > 0) {
            ir0 = rg[0]; ir1 = rg[1]; ir2 = rg[2]; ir3 = rg[3]; ir4 = rg[4];
            rg[0] = 0.f; rg[1] = 0.f; rg[2] = 0.f; rg[3] = 0.f; rg[4] = 0.f;
        }

        // ---- psc recurrence + input current (k ascending, ref order) -------
        const float* xp  = x_t + (size_t)n * NB_;
        float*       pp  = psc + (size_t)n * NB_;
        const float* sdp = sd  + (size_t)n * NB_;
        const float* pip = pi  + (size_t)n * NB_;
        float ic = 0.0f, pv;
        pv = pp[0] * sdp[0] + (ir0 + xp[0]) * pip[0]; pp[0] = pv; ic += pv;
        pv = pp[1] * sdp[1] + (ir1 + xp[1]) * pip[1]; pp[1] = pv; ic += pv;
        pv = pp[2] * sdp[2] + (ir2 + xp[2]) * pip[2]; pp[2] = pv; ic += pv;
        pv = pp[3] * sdp[3] + (ir3 + xp[3]) * pip[3]; pp[3] = pv; ic += pv;
        pv = pp[4] * sdp[4] + (ir4 + xp[4]) * pip[4]; pp[4] = pv; ic += pv;

        float4 P0 = pk[3 * n], P1 = pk[3 * n + 1], P2 = pk[3 * n + 2];

        float pz = (t > 0) ? out_prev[n] : 0.0f;

        float a0 = P1.w * asc[2 * n]     + pz * P2.y;
        float a1 = P2.x * asc[2 * n + 1] + pz * P2.z;
        asc[2 * n]     = a0;
        asc[2 * n + 1] = a1;

        float c1 = ic + (a0 + a1) + P0.z;
        float nv = P0.x * v[n] + P0.y * c1;
        if (pz > 0.5f) nv = P1.x;

        float vsc = (nv - P0.w) / P1.y;
        z = (vsc > 0.0f) ? 1.0f : 0.0f;
        float rr = r[n];
        if (rr > 0.0f) z = 0.0f;

        r[n] = fmaxf(rr + z * P1.z - 1.0f, 0.0f);   // DT = 1.0
        v[n] = nv;
        out_t[n] = z;

        // enqueue this neuron's outgoing row for the cooperative push
        if (z != 0.0f) {
            int idx = atomicAdd(&nf_s, 1);
            rowsL[idx] = rp[n];
        }
    }

    // per-step spike count (one atomic per spiking wave)
    unsigned long long m = __ballot(z != 0.0f);
    if ((tloc & 63) == 0 && m)
        atomicAdd(scnt_new, (int)__popcll(m));

    __syncthreads();
    int nf = nf_s;                 // uniform across block
    if (nf == 0) return;

    // ---- prefix-sum of firing rows' edge counts -----------------------------
    int cnt = (tloc < nf) ? (int)(rowsL[tloc].y - rowsL[tloc].x) : 0;
    scL[tloc] = cnt;
    __syncthreads();
    int x = cnt;
    for (int off = 1; off < 256; off <<= 1) {
        int y = (tloc >= off) ? scL[tloc - off] : 0;
        __syncthreads();
        x += y;
        scL[tloc] = x;
        __syncthreads();
    }
    pref[tloc + 1] = scL[tloc];
    if (tloc == 0) pref[0] = 0;
    __syncthreads();

    // ---- all 256 threads process the union of firing edges ------------------
    int tot = pref[nf];
    for (int j = tloc; j < tot; j += 256) {
        int lo = 0, hi = nf - 1;                 // largest row with pref[row] <= j
        while (lo < hi) {
            int mid = (lo + hi + 1) >> 1;
            if (pref[mid] <= j) lo = mid; else hi = mid - 1;
        }
        int i = (int)rowsL[lo].x + (j - pref[lo]);
        unsigned q = edgeRec[i];
        int d = (int)((q >> 21) & 7u);
        int e = (int)(q & 0x1FFFFFu);
        float w = weights[e];
        const float* bs = edge_basis + (size_t)e * NB_;
        float* dst = ring + (size_t)((t + 1 + d) % RING) * n5
                   + (size_t)post_idx[e] * NB_;
        atomicAdd(dst + 0, w * bs[0]);
        atomicAdd(dst + 1, w * bs[1]);
        atomicAdd(dst + 2, w * bs[2]);
        atomicAdd(dst + 3, w * bs[3]);
        atomicAdd(dst + 4, w * bs[4]);
    }
}

// ---------------------------------------------------------------------------
// Launcher
// ---------------------------------------------------------------------------

extern "C" void kernel_launch(void* const* d_in, const int* in_sizes, int n_in,
                              void* d_out, int out_size, void* d_ws, size_t ws_size,
                              hipStream_t stream)
{
    const float* weights        = (const float*)d_in[0];
    const float* edge_basis     = (const float*)d_in[1];
    const float* ext_input      = (const float*)d_in[2];
    const float* decay          = (const float*)d_in[3];
    const float* current_factor = (const float*)d_in[4];
    const float* gathered_g     = (const float*)d_in[5];
    const float* v_th           = (const float*)d_in[6];
    const float* v_reset        = (const float*)d_in[7];
    const float* normalizer     = (const float*)d_in[8];
    const float* t_ref          = (const float*)d_in[9];
    const float* exp_dt_k       = (const float*)d_in[10];
    const float* asc_amps       = (const float*)d_in[11];
    const float* syn_decay      = (const float*)d_in[12];
    const float* psc_initial    = (const float*)d_in[13];
    const int*   pre_idx        = (const int*)d_in[14];
    const int*   post_idx       = (const int*)d_in[15];

    const int E  = in_sizes[0];
    const int N  = in_sizes[3];
    const int n5 = N * NB_;
    const int T  = in_sizes[2] / n5;            // B = 1

    const int NC = (N + CSL - 1) / CSL;         // 391

    float* out = (float*)d_out;

    // ---- workspace layout ---------------------------------------------------
    char* wsb = (char*)d_ws;
    size_t o = 0;
    // zero group (one memset):
    int*   gcur = (int*)(wsb + o);   o += 512 * 4;
    int*   scnt = (int*)(wsb + o);   o += (size_t)(T + MD_) * 4;
    o = (o + 15) & ~(size_t)15;
    float* psc  = (float*)(wsb + o); o += (size_t)n5 * 4;
    float* r    = (float*)(wsb + o); o += (size_t)N * 4;
    float* asc  = (float*)(wsb + o); o += (size_t)2 * N * 4;
    o = (o + 15) & ~(size_t)15;
    float* ring = (float*)(wsb + o); o += (size_t)RING * n5 * 4;
    size_t zero_bytes = o;                      // ~7.9 MB
    // non-zeroed:
    float*  v       = (float*)(wsb + o);  o += (size_t)N * 4;
    float4* pk      = (float4*)(wsb + o); o += (size_t)N * 12 * 4;
    uint2*  rp      = (uint2*)(wsb + o);  o += (size_t)N * 8;
    o = (o + 15) & ~(size_t)15;
    unsigned* part    = (unsigned*)(wsb + o); o += (size_t)NC * CAP * 4;
    unsigned* edgeRec = (unsigned*)(wsb + o); o += (size_t)NC * CAP * 4;

    // ---- build (every launch; graph replays everything) --------------------
    hipMemsetAsync(d_ws, 0, zero_bytes, stream);

    const int nbe = (E + CH2 - 1) / CH2;   // 245
    partition_kernel<<<nbe, 256, 0, stream>>>(pre_idx, gcur, part, E, N);
    bucket_sort_kernel<<<NC, 256, 0, stream>>>(
        gcur, part, edgeRec, rp,
        decay, current_factor, gathered_g, v_th, v_reset, normalizer, t_ref,
        exp_dt_k, asc_amps, pk, v, N);

    // ---- time loop: ONE kernel per step -------------------------------------
    const int nblk = (N + 255) / 256;    // 196
    for (int t = 0; t < T; ++t) {
        step_kernel<<<nblk, 256, 0, stream>>>(
            ext_input + (size_t)t * n5,
            psc, syn_decay, psc_initial,
            pk, v, r, asc,
            ring, scnt, scnt + MD_ + t,
            out + (size_t)(t > 0 ? t - 1 : 0) * N,
            out + (size_t)t * N,
            rp, edgeRec, weights, edge_basis, post_idx,
            t, n5, N);
    }
}

// Round 15
// 251.491 us; speedup vs baseline: 1.0943x; 1.0943x over previous
//
#include <hip/hip_runtime.h>

#define NB_ 5      // N_BASIS
#define MD_ 5      // MAX_DELAY
#define CSL 128    // pre-neurons per coarse bucket (power of 2)
#define CAP 6144   // records per bucket (avg 5120 at E=2M,N=50k; +14 sigma)
#define CH2 4096   // edges per partition block (LDS sort tile)
#define RING 6     // i_rec ring slots (current + 5 future)

// ---------------------------------------------------------------------------
// Build: edges sorted by PRE neuron (outgoing CSR), 4-byte records.
//   record u32 = localn(7) << 24 | d(3) << 21 | eid(21)     (E=2M < 2^21)
//   rp[n] = {start, end} absolute indices into edgeRec (bucket-padded layout)
// ---------------------------------------------------------------------------

// Block-level counting sort by coarse bucket (n>>7), then STREAMING copy to
// the bucket's reserved global run. CH2=4096 keeps LDS ~33 KB so multiple
// blocks co-reside per CU (round-14's 58 KB capped occupancy at 8%).
__global__ __launch_bounds__(256) void partition_kernel(
    const int* __restrict__ pre_idx,
    int* __restrict__ gcur,           // 512 cursors (zeroed)
    unsigned* __restrict__ part,      // NC*CAP
    int E, int N)
{
    __shared__ unsigned srt[CH2];          // 16 KB sorted records
    __shared__ unsigned short bkt[CH2];    //  8 KB bucket tag per slot
    __shared__ int hist[512];
    __shared__ int lbase[512];
    __shared__ int pos[512];
    __shared__ int gbase[512];
    __shared__ int tmp[256];

    const int t  = threadIdx.x;
    const int e0 = blockIdx.x * CH2;
    const int cnt = min(CH2, E - e0);

    hist[t] = 0; hist[t + 256] = 0;
    __syncthreads();

    // pass 1: histogram over coarse buckets
    for (int i = t; i < cnt; i += 256) {
        int pre = pre_idx[e0 + i];
        int d = pre / N;
        int n = pre - d * N;
        atomicAdd(&hist[n >> 7], 1);
    }
    __syncthreads();

    // exclusive scan of hist[0..511] (2 entries per thread)
    int a = hist[2 * t], b = hist[2 * t + 1], s = a + b;
    tmp[t] = s;
    __syncthreads();
    int x = s;
    for (int off = 1; off < 256; off <<= 1) {
        int y = (t >= off) ? tmp[t - off] : 0;
        __syncthreads();
        x += y;
        tmp[t] = x;
        __syncthreads();
    }
    int ep = x - s;
    lbase[2 * t] = ep;         pos[2 * t] = ep;
    lbase[2 * t + 1] = ep + a; pos[2 * t + 1] = ep + a;
    // reserve global runs (one atomic per non-empty bucket)
    gbase[2 * t]     = a ? atomicAdd(&gcur[2 * t], a) : 0;
    gbase[2 * t + 1] = b ? atomicAdd(&gcur[2 * t + 1], b) : 0;
    __syncthreads();

    // pass 2: scatter into LDS sorted order (pre_idx re-read is L2-hot)
    for (int i = t; i < cnt; i += 256) {
        int pre = pre_idx[e0 + i];
        int d = pre / N;
        int n = pre - d * N;
        int bk = n >> 7;
        int p = atomicAdd(&pos[bk], 1);
        srt[p] = ((unsigned)(n & (CSL - 1)) << 24) | ((unsigned)d << 21)
               | (unsigned)(e0 + i);
        bkt[p] = (unsigned short)bk;
    }
    __syncthreads();

    // pass 3: linear copy — same-bucket runs contiguous in LDS and global.
    for (int j = t; j < cnt; j += 256) {
        int bk = bkt[j];
        int off2 = gbase[bk] + (j - lbase[bk]);
        if (off2 < CAP)   // never triggers for uniform pre_idx (+14 sigma)
            part[(size_t)bk * CAP + off2] = srt[j];
    }
}

// one block per coarse bucket: LDS counting sort over CSL local pre-neurons.
// Also performs per-neuron parameter packing (absorbed init_kernel).
__global__ __launch_bounds__(256) void bucket_sort_kernel(
    const int* __restrict__ gcur,
    const unsigned* __restrict__ part,
    unsigned* __restrict__ edgeRec,   // NC*CAP
    uint2* __restrict__ rp,           // per-neuron {start,end}
    const float* __restrict__ decay, const float* __restrict__ cf,
    const float* __restrict__ g,     const float* __restrict__ vth,
    const float* __restrict__ vrst,  const float* __restrict__ nrm,
    const float* __restrict__ tref,  const float* __restrict__ ek,
    const float* __restrict__ am,
    float4* __restrict__ pk, float* __restrict__ v,
    int N)
{
    __shared__ int h[CSL];
    __shared__ int sc_[CSL];
    __shared__ int pos_[CSL];
    int c = blockIdx.x, t = threadIdx.x;

    // ---- absorbed init: this block packs params for its 128 neurons --------
    if (t < CSL) {
        int n = c * CSL + t;
        if (n < N) {
            pk[3 * n]     = make_float4(decay[n], cf[n], g[n], vth[n]);
            pk[3 * n + 1] = make_float4(vrst[n], nrm[n], tref[n], ek[2 * n]);
            pk[3 * n + 2] = make_float4(ek[2 * n + 1], am[2 * n], am[2 * n + 1], 0.0f);
            v[n] = vrst[n];
        }
    }

    int cnt = min(gcur[c], CAP);
    size_t base = (size_t)c * CAP;
    if (t < CSL) h[t] = 0;
    __syncthreads();
    for (int i = t; i < cnt; i += 256)
        atomicAdd(&h[part[base + i] >> 24], 1);
    __syncthreads();
    if (t < CSL) sc_[t] = h[t];
    __syncthreads();
    for (int off = 1; off < CSL; off <<= 1) {
        int y = 0;
        if (t < CSL && t >= off) y = sc_[t - off];
        __syncthreads();
        if (t < CSL && t >= off) sc_[t] += y;
        __syncthreads();
    }
    if (t < CSL) {
        int end = sc_[t];                 // inclusive end (local)
        pos_[t] = (int)base + end - h[t]; // exclusive start (absolute)
        int gn = c * CSL + t;
        if (gn < N)
            rp[gn] = make_uint2((unsigned)(base + end - h[t]),
                                (unsigned)(base + end));
    }
    __syncthreads();
    for (int i = t; i < cnt; i += 256) {
        unsigned q = part[base + i];
        int dst = atomicAdd(&pos_[q >> 24], 1);
        edgeRec[dst] = q;
    }
}

// ---------------------------------------------------------------------------
// Per-step kernel: neuron update + WAVE-COOPERATIVE push of firing neurons'
// outgoing edges into future i_rec ring slots. One dispatch per step.
// No LDS, no __syncthreads — pure wave-level coordination.
// ---------------------------------------------------------------------------

__global__ __launch_bounds__(256) void step_kernel(
    const float* __restrict__ x_t,        // ext_input + t*n5
    float*       __restrict__ psc,        // n5
    const float* __restrict__ sd,         // syn_decay
    const float* __restrict__ pi,         // psc_initial
    const float4* __restrict__ pk,        // {decay,cf,g,vth}{vrst,nrm,tref,ek0}{ek1,am0,am1,_}
    float* __restrict__ v,
    float* __restrict__ r,
    float* __restrict__ asc,              // (N,2)
    float* __restrict__ ring,             // RING*n5 i_rec accumulators
    const int* __restrict__ scnt,         // scnt[MD+u] = spike count of step u
    int*       __restrict__ scnt_new,     // &scnt[MD+t]
    const float* __restrict__ out_prev,   // out + (t-1)*N (t>=1)
    float*       __restrict__ out_t,      // out + t*N
    const uint2*    __restrict__ rp,      // outgoing CSR {start,end}
    const unsigned* __restrict__ edgeRec,
    const float*    __restrict__ weights,
    const float*    __restrict__ edge_basis,
    const int*      __restrict__ post_idx,
    int t, int n5, int N)
{
    const int tloc = threadIdx.x;
    const int n = blockIdx.x * blockDim.x + tloc;
    const bool has = (n < N);
    const int lane = tloc & 63;

    // spike count in window t-5..t-1 (scnt offset by MD, head zeroed)
    const int* sw = scnt + t;
    int scw = sw[0] + sw[1] + sw[2] + sw[3] + sw[4];

    float z = 0.0f;
    if (has) {
        // ---- read & clear this step's i_rec ring slot (skip when quiet) ----
        float ir0 = 0.f, ir1 = 0.f, ir2 = 0.f, ir3 = 0.f, ir4 = 0.f;
        float* rg = ring + (size_t)(t % RING) * n5 + (size_t)n * NB_;
        if (scw > 0) {
            ir0 = rg[0]; ir1 = rg[1]; ir2 = rg[2]; ir3 = rg[3]; ir4 = rg[4];
            rg[0] = 0.f; rg[1] = 0.f; rg[2] = 0.f; rg[3] = 0.f; rg[4] = 0.f;
        }

        // ---- psc recurrence + input current (k ascending, ref order) -------
        const float* xp  = x_t + (size_t)n * NB_;
        float*       pp  = psc + (size_t)n * NB_;
        const float* sdp = sd  + (size_t)n * NB_;
        const float* pip = pi  + (size_t)n * NB_;
        float ic = 0.0f, pv;
        pv = pp[0] * sdp[0] + (ir0 + xp[0]) * pip[0]; pp[0] = pv; ic += pv;
        pv = pp[1] * sdp[1] + (ir1 + xp[1]) * pip[1]; pp[1] = pv; ic += pv;
        pv = pp[2] * sdp[2] + (ir2 + xp[2]) * pip[2]; pp[2] = pv; ic += pv;
        pv = pp[3] * sdp[3] + (ir3 + xp[3]) * pip[3]; pp[3] = pv; ic += pv;
        pv = pp[4] * sdp[4] + (ir4 + xp[4]) * pip[4]; pp[4] = pv; ic += pv;

        float4 P0 = pk[3 * n], P1 = pk[3 * n + 1], P2 = pk[3 * n + 2];

        float pz = (t > 0) ? out_prev[n] : 0.0f;

        float a0 = P1.w * asc[2 * n]     + pz * P2.y;
        float a1 = P2.x * asc[2 * n + 1] + pz * P2.z;
        asc[2 * n]     = a0;
        asc[2 * n + 1] = a1;

        float c1 = ic + (a0 + a1) + P0.z;
        float nv = P0.x * v[n] + P0.y * c1;
        if (pz > 0.5f) nv = P1.x;

        float vsc = (nv - P0.w) / P1.y;
        z = (vsc > 0.0f) ? 1.0f : 0.0f;
        float rr = r[n];
        if (rr > 0.0f) z = 0.0f;

        r[n] = fmaxf(rr + z * P1.z - 1.0f, 0.0f);   // DT = 1.0
        v[n] = nv;
        out_t[n] = z;
    }

    // ---- wave-level spike bookkeeping + cooperative push --------------------
    unsigned long long fm = __ballot(z != 0.0f);
    if (lane == 0 && fm)
        atomicAdd(scnt_new, (int)__popcll(fm));

    if (fm) {
        // firing lanes fetch their CSR row; others hold junk (never selected)
        unsigned rs0 = 0, re0 = 0;
        if (z != 0.0f) { uint2 row = rp[n]; rs0 = row.x; re0 = row.y; }

        // iterate firing lanes (wave-uniform loop); 64 lanes share each row
        unsigned long long fm2 = fm;
        while (fm2) {
            int src = (int)(__ffsll((long long)fm2) - 1);
            fm2 &= fm2 - 1;
            unsigned rs = __shfl(rs0, src);
            unsigned re = __shfl(re0, src);
            for (unsigned i = rs + lane; i < re; i += 64) {
                unsigned q = edgeRec[i];
                int d = (int)((q >> 21) & 7u);
                int e = (int)(q & 0x1FFFFFu);
                float w = weights[e];
                const float* bs = edge_basis + (size_t)e * NB_;
                float* dst = ring + (size_t)((t + 1 + d) % RING) * n5
                           + (size_t)post_idx[e] * NB_;
                atomicAdd(dst + 0, w * bs[0]);
                atomicAdd(dst + 1, w * bs[1]);
                atomicAdd(dst + 2, w * bs[2]);
                atomicAdd(dst + 3, w * bs[3]);
                atomicAdd(dst + 4, w * bs[4]);
            }
        }
    }
}

// ---------------------------------------------------------------------------
// Launcher
// ---------------------------------------------------------------------------

extern "C" void kernel_launch(void* const* d_in, const int* in_sizes, int n_in,
                              void* d_out, int out_size, void* d_ws, size_t ws_size,
                              hipStream_t stream)
{
    const float* weights        = (const float*)d_in[0];
    const float* edge_basis     = (const float*)d_in[1];
    const float* ext_input      = (const float*)d_in[2];
    const float* decay          = (const float*)d_in[3];
    const float* current_factor = (const float*)d_in[4];
    const float* gathered_g     = (const float*)d_in[5];
    const float* v_th           = (const float*)d_in[6];
    const float* v_reset        = (const float*)d_in[7];
    const float* normalizer     = (const float*)d_in[8];
    const float* t_ref          = (const float*)d_in[9];
    const float* exp_dt_k       = (const float*)d_in[10];
    const float* asc_amps       = (const float*)d_in[11];
    const float* syn_decay      = (const float*)d_in[12];
    const float* psc_initial    = (const float*)d_in[13];
    const int*   pre_idx        = (const int*)d_in[14];
    const int*   post_idx       = (const int*)d_in[15];

    const int E  = in_sizes[0];
    const int N  = in_sizes[3];
    const int n5 = N * NB_;
    const int T  = in_sizes[2] / n5;            // B = 1

    const int NC = (N + CSL - 1) / CSL;         // 391

    float* out = (float*)d_out;

    // ---- workspace layout ---------------------------------------------------
    char* wsb = (char*)d_ws;
    size_t o = 0;
    // zero group (one memset):
    int*   gcur = (int*)(wsb + o);   o += 512 * 4;
    int*   scnt = (int*)(wsb + o);   o += (size_t)(T + MD_) * 4;
    o = (o + 15) & ~(size_t)15;
    float* psc  = (float*)(wsb + o); o += (size_t)n5 * 4;
    float* r    = (float*)(wsb + o); o += (size_t)N * 4;
    float* asc  = (float*)(wsb + o); o += (size_t)2 * N * 4;
    o = (o + 15) & ~(size_t)15;
    float* ring = (float*)(wsb + o); o += (size_t)RING * n5 * 4;
    size_t zero_bytes = o;                      // ~7.9 MB
    // non-zeroed:
    float*  v       = (float*)(wsb + o);  o += (size_t)N * 4;
    float4* pk      = (float4*)(wsb + o); o += (size_t)N * 12 * 4;
    uint2*  rp      = (uint2*)(wsb + o);  o += (size_t)N * 8;
    o = (o + 15) & ~(size_t)15;
    unsigned* part    = (unsigned*)(wsb + o); o += (size_t)NC * CAP * 4;
    unsigned* edgeRec = (unsigned*)(wsb + o); o += (size_t)NC * CAP * 4;

    // ---- build (every launch; graph replays everything) --------------------
    hipMemsetAsync(d_ws, 0, zero_bytes, stream);

    const int nbe = (E + CH2 - 1) / CH2;   // 489
    partition_kernel<<<nbe, 256, 0, stream>>>(pre_idx, gcur, part, E, N);
    bucket_sort_kernel<<<NC, 256, 0, stream>>>(
        gcur, part, edgeRec, rp,
        decay, current_factor, gathered_g, v_th, v_reset, normalizer, t_ref,
        exp_dt_k, asc_amps, pk, v, N);

    // ---- time loop: ONE kernel per step -------------------------------------
    const int nblk = (N + 255) / 256;    // 196
    for (int t = 0; t < T; ++t) {
        step_kernel<<<nblk, 256, 0, stream>>>(
            ext_input + (size_t)t * n5,
            psc, syn_decay, psc_initial,
            pk, v, r, asc,
            ring, scnt, scnt + MD_ + t,
            out + (size_t)(t > 0 ? t - 1 : 0) * N,
            out + (size_t)t * N,
            rp, edgeRec, weights, edge_basis, post_idx,
            t, n5, N);
    }
}

// Round 16
// 235.410 us; speedup vs baseline: 1.1690x; 1.0683x over previous
//
#include <hip/hip_runtime.h>

#define NB_ 5      // N_BASIS
#define MD_ 5      // MAX_DELAY
#define CSL 128    // pre-neurons per coarse bucket (power of 2)
#define CAP 6144   // records per bucket (avg 5120 at E=2M,N=50k; +14 sigma)
#define CH2 4096   // edges per partition block (LDS sort tile)
#define RING 6     // i_rec ring slots (current + 5 future)

// ---------------------------------------------------------------------------
// Build: edges sorted by PRE neuron (outgoing CSR), 4-byte records.
//   record u32 = localn(7) << 24 | d(3) << 21 | eid(21)     (E=2M < 2^21)
// Packed per-neuron records produced by bucket_sort:
//   constC[6n+0..5] = {sd0..3}{sd4,pi0..2}{pi3,pi4,dec,cf}{g,vth,vrst,nrm}
//                     {tref,ek0,ek1,am0}{am1, bits(row_start), bits(row_end), 0}
//   state [3n+0..2] = {psc0..3}{psc4,asc0,asc1,v}{r, z, 0, 0}
// ---------------------------------------------------------------------------

__global__ __launch_bounds__(256) void partition_kernel(
    const int* __restrict__ pre_idx,
    int* __restrict__ gcur,           // 512 cursors (zeroed)
    unsigned* __restrict__ part,      // NC*CAP
    int E, int N)
{
    __shared__ unsigned srt[CH2];          // 16 KB sorted records
    __shared__ unsigned short bkt[CH2];    //  8 KB bucket tag per slot
    __shared__ int hist[512];
    __shared__ int lbase[512];
    __shared__ int pos[512];
    __shared__ int gbase[512];
    __shared__ int tmp[256];

    const int t  = threadIdx.x;
    const int e0 = blockIdx.x * CH2;
    const int cnt = min(CH2, E - e0);

    hist[t] = 0; hist[t + 256] = 0;
    __syncthreads();

    for (int i = t; i < cnt; i += 256) {
        int pre = pre_idx[e0 + i];
        int d = pre / N;
        int n = pre - d * N;
        atomicAdd(&hist[n >> 7], 1);
    }
    __syncthreads();

    int a = hist[2 * t], b = hist[2 * t + 1], s = a + b;
    tmp[t] = s;
    __syncthreads();
    int x = s;
    for (int off = 1; off < 256; off <<= 1) {
        int y = (t >= off) ? tmp[t - off] : 0;
        __syncthreads();
        x += y;
        tmp[t] = x;
        __syncthreads();
    }
    int ep = x - s;
    lbase[2 * t] = ep;         pos[2 * t] = ep;
    lbase[2 * t + 1] = ep + a; pos[2 * t + 1] = ep + a;
    gbase[2 * t]     = a ? atomicAdd(&gcur[2 * t], a) : 0;
    gbase[2 * t + 1] = b ? atomicAdd(&gcur[2 * t + 1], b) : 0;
    __syncthreads();

    for (int i = t; i < cnt; i += 256) {
        int pre = pre_idx[e0 + i];
        int d = pre / N;
        int n = pre - d * N;
        int bk = n >> 7;
        int p = atomicAdd(&pos[bk], 1);
        srt[p] = ((unsigned)(n & (CSL - 1)) << 24) | ((unsigned)d << 21)
               | (unsigned)(e0 + i);
        bkt[p] = (unsigned short)bk;
    }
    __syncthreads();

    for (int j = t; j < cnt; j += 256) {
        int bk = bkt[j];
        int off2 = gbase[bk] + (j - lbase[bk]);
        if (off2 < CAP)
            part[(size_t)bk * CAP + off2] = srt[j];
    }
}

// one block per coarse bucket: LDS counting sort over CSL local pre-neurons.
// Also emits the packed constC/state records (absorbed init).
__global__ __launch_bounds__(256) void bucket_sort_kernel(
    const int* __restrict__ gcur,
    const unsigned* __restrict__ part,
    unsigned* __restrict__ edgeRec,   // NC*CAP
    const float* __restrict__ decay, const float* __restrict__ cf,
    const float* __restrict__ g,     const float* __restrict__ vth,
    const float* __restrict__ vrst,  const float* __restrict__ nrm,
    const float* __restrict__ tref,  const float* __restrict__ ek,
    const float* __restrict__ am,
    const float* __restrict__ sd,    const float* __restrict__ pi,
    float4* __restrict__ constC, float4* __restrict__ state,
    int N)
{
    __shared__ int h[CSL];
    __shared__ int sc_[CSL];
    __shared__ int pos_[CSL];
    int c = blockIdx.x, t = threadIdx.x;

    int cnt = min(gcur[c], CAP);
    size_t base = (size_t)c * CAP;
    if (t < CSL) h[t] = 0;
    __syncthreads();
    for (int i = t; i < cnt; i += 256)
        atomicAdd(&h[part[base + i] >> 24], 1);
    __syncthreads();
    if (t < CSL) sc_[t] = h[t];
    __syncthreads();
    for (int off = 1; off < CSL; off <<= 1) {
        int y = 0;
        if (t < CSL && t >= off) y = sc_[t - off];
        __syncthreads();
        if (t < CSL && t >= off) sc_[t] += y;
        __syncthreads();
    }
    if (t < CSL) {
        int end = sc_[t];                 // inclusive end (local)
        pos_[t] = (int)base + end - h[t]; // exclusive start (absolute)
        int n = c * CSL + t;
        if (n < N) {
            unsigned rs = (unsigned)(base + end - h[t]);
            unsigned re = (unsigned)(base + end);
            // ---- packed const record (6 x float4) ---------------------------
            const float* sdp = sd + (size_t)n * NB_;
            const float* pip = pi + (size_t)n * NB_;
            constC[6 * (size_t)n + 0] = make_float4(sdp[0], sdp[1], sdp[2], sdp[3]);
            constC[6 * (size_t)n + 1] = make_float4(sdp[4], pip[0], pip[1], pip[2]);
            constC[6 * (size_t)n + 2] = make_float4(pip[3], pip[4], decay[n], cf[n]);
            constC[6 * (size_t)n + 3] = make_float4(g[n], vth[n], vrst[n], nrm[n]);
            constC[6 * (size_t)n + 4] = make_float4(tref[n], ek[2 * n], ek[2 * n + 1], am[2 * n]);
            constC[6 * (size_t)n + 5] = make_float4(am[2 * n + 1],
                                                    __uint_as_float(rs),
                                                    __uint_as_float(re), 0.0f);
            // ---- state init (3 x float4) ------------------------------------
            state[3 * (size_t)n + 0] = make_float4(0.f, 0.f, 0.f, 0.f);
            state[3 * (size_t)n + 1] = make_float4(0.f, 0.f, 0.f, vrst[n]);
            state[3 * (size_t)n + 2] = make_float4(0.f, 0.f, 0.f, 0.f);
        }
    }
    __syncthreads();
    for (int i = t; i < cnt; i += 256) {
        unsigned q = part[base + i];
        int dst = atomicAdd(&pos_[q >> 24], 1);
        edgeRec[dst] = q;
    }
}

// ---------------------------------------------------------------------------
// Per-step kernel: packed-record neuron update + wave-cooperative push.
// Math textually identical to round 15 (bit-exact).
// ---------------------------------------------------------------------------

__global__ __launch_bounds__(256) void step_kernel(
    const float* __restrict__ x_t,        // ext_input + t*n5
    const float4* __restrict__ constC,    // 6 per neuron
    float4*       __restrict__ state,     // 3 per neuron
    float* __restrict__ ring,             // RING*n5 i_rec accumulators
    const int* __restrict__ scnt,         // scnt[MD+u] = spike count of step u
    int*       __restrict__ scnt_new,     // &scnt[MD+t]
    float*       __restrict__ out_t,      // out + t*N
    const unsigned* __restrict__ edgeRec,
    const float*    __restrict__ weights,
    const float*    __restrict__ edge_basis,
    const int*      __restrict__ post_idx,
    int t, int n5, int N)
{
    const int tloc = threadIdx.x;
    const int n = blockIdx.x * blockDim.x + tloc;
    const bool has = (n < N);
    const int lane = tloc & 63;

    // spike count in window t-5..t-1 (scnt offset by MD, head zeroed)
    const int* sw = scnt + t;
    int scw = sw[0] + sw[1] + sw[2] + sw[3] + sw[4];

    float z = 0.0f;
    unsigned rs0 = 0, re0 = 0;
    if (has) {
        // ---- packed loads ---------------------------------------------------
        float4 C0 = constC[6 * (size_t)n + 0];
        float4 C1 = constC[6 * (size_t)n + 1];
        float4 C2 = constC[6 * (size_t)n + 2];
        float4 C3 = constC[6 * (size_t)n + 3];
        float4 C4 = constC[6 * (size_t)n + 4];
        float4 S0 = state[3 * (size_t)n + 0];
        float4 S1 = state[3 * (size_t)n + 1];
        float4 S2 = state[3 * (size_t)n + 2];

        // ---- read & clear this step's i_rec ring slot (skip when quiet) ----
        float ir0 = 0.f, ir1 = 0.f, ir2 = 0.f, ir3 = 0.f, ir4 = 0.f;
        float* rg = ring + (size_t)(t % RING) * n5 + (size_t)n * NB_;
        if (scw > 0) {
            ir0 = rg[0]; ir1 = rg[1]; ir2 = rg[2]; ir3 = rg[3]; ir4 = rg[4];
            rg[0] = 0.f; rg[1] = 0.f; rg[2] = 0.f; rg[3] = 0.f; rg[4] = 0.f;
        }

        // ---- psc recurrence + input current (k ascending, ref order) -------
        const float* xp = x_t + (size_t)n * NB_;
        float ic = 0.0f, pv;
        float p0, p1, p2, p3, p4;
        pv = S0.x * C0.x + (ir0 + xp[0]) * C1.y; p0 = pv; ic += pv;
        pv = S0.y * C0.y + (ir1 + xp[1]) * C1.z; p1 = pv; ic += pv;
        pv = S0.z * C0.z + (ir2 + xp[2]) * C1.w; p2 = pv; ic += pv;
        pv = S0.w * C0.w + (ir3 + xp[3]) * C2.x; p3 = pv; ic += pv;
        pv = S1.x * C1.x + (ir4 + xp[4]) * C2.y; p4 = pv; ic += pv;

        float pz = S2.y;

        float a0 = C4.y * S1.y + pz * C4.w;
        float a1 = C4.z * S1.z + pz * ((float4&)constC[6 * (size_t)n + 5]).x;
        // NOTE: C5.x is am1; loaded below together with row ptrs
        float4 C5 = constC[6 * (size_t)n + 5];
        a1 = C4.z * S1.z + pz * C5.x;

        float c1 = ic + (a0 + a1) + C3.x;
        float nv = C2.z * S1.w + C2.w * c1;
        if (pz > 0.5f) nv = C3.z;

        float vsc = (nv - C3.y) / C3.w;
        z = (vsc > 0.0f) ? 1.0f : 0.0f;
        float rr = S2.x;
        if (rr > 0.0f) z = 0.0f;

        float nr = fmaxf(rr + z * C4.x - 1.0f, 0.0f);   // DT = 1.0

        state[3 * (size_t)n + 0] = make_float4(p0, p1, p2, p3);
        state[3 * (size_t)n + 1] = make_float4(p4, a0, a1, nv);
        state[3 * (size_t)n + 2] = make_float4(nr, z, 0.0f, 0.0f);
        out_t[n] = z;

        rs0 = __float_as_uint(C5.y);
        re0 = __float_as_uint(C5.z);
    }

    // ---- wave-level spike bookkeeping + cooperative push --------------------
    unsigned long long fm = __ballot(z != 0.0f);
    if (lane == 0 && fm)
        atomicAdd(scnt_new, (int)__popcll(fm));

    if (fm) {
        unsigned long long fm2 = fm;
        while (fm2) {
            int src = (int)(__ffsll((long long)fm2) - 1);
            fm2 &= fm2 - 1;
            unsigned rs = __shfl(rs0, src);
            unsigned re = __shfl(re0, src);
            for (unsigned i = rs + lane; i < re; i += 64) {
                unsigned q = edgeRec[i];
                int d = (int)((q >> 21) & 7u);
                int e = (int)(q & 0x1FFFFFu);
                float w = weights[e];
                const float* bs = edge_basis + (size_t)e * NB_;
                float* dst = ring + (size_t)((t + 1 + d) % RING) * n5
                           + (size_t)post_idx[e] * NB_;
                atomicAdd(dst + 0, w * bs[0]);
                atomicAdd(dst + 1, w * bs[1]);
                atomicAdd(dst + 2, w * bs[2]);
                atomicAdd(dst + 3, w * bs[3]);
                atomicAdd(dst + 4, w * bs[4]);
            }
        }
    }
}

// ---------------------------------------------------------------------------
// Launcher
// ---------------------------------------------------------------------------

extern "C" void kernel_launch(void* const* d_in, const int* in_sizes, int n_in,
                              void* d_out, int out_size, void* d_ws, size_t ws_size,
                              hipStream_t stream)
{
    const float* weights        = (const float*)d_in[0];
    const float* edge_basis     = (const float*)d_in[1];
    const float* ext_input      = (const float*)d_in[2];
    const float* decay          = (const float*)d_in[3];
    const float* current_factor = (const float*)d_in[4];
    const float* gathered_g     = (const float*)d_in[5];
    const float* v_th           = (const float*)d_in[6];
    const float* v_reset        = (const float*)d_in[7];
    const float* normalizer     = (const float*)d_in[8];
    const float* t_ref          = (const float*)d_in[9];
    const float* exp_dt_k       = (const float*)d_in[10];
    const float* asc_amps       = (const float*)d_in[11];
    const float* syn_decay      = (const float*)d_in[12];
    const float* psc_initial    = (const float*)d_in[13];
    const int*   pre_idx        = (const int*)d_in[14];
    const int*   post_idx       = (const int*)d_in[15];

    const int E  = in_sizes[0];
    const int N  = in_sizes[3];
    const int n5 = N * NB_;
    const int T  = in_sizes[2] / n5;            // B = 1

    const int NC = (N + CSL - 1) / CSL;         // 391

    float* out = (float*)d_out;

    // ---- workspace layout ---------------------------------------------------
    char* wsb = (char*)d_ws;
    size_t o = 0;
    // zero group (one memset):
    int*   gcur = (int*)(wsb + o);   o += 512 * 4;
    int*   scnt = (int*)(wsb + o);   o += (size_t)(T + MD_) * 4;
    o = (o + 15) & ~(size_t)15;
    float* ring = (float*)(wsb + o); o += (size_t)RING * n5 * 4;
    size_t zero_bytes = o;                      // ~6 MB
    // non-zeroed:
    float4* constC = (float4*)(wsb + o); o += (size_t)N * 6 * 16;
    float4* state  = (float4*)(wsb + o); o += (size_t)N * 3 * 16;
    unsigned* part    = (unsigned*)(wsb + o); o += (size_t)NC * CAP * 4;
    unsigned* edgeRec = (unsigned*)(wsb + o); o += (size_t)NC * CAP * 4;

    // ---- build (every launch; graph replays everything) --------------------
    hipMemsetAsync(d_ws, 0, zero_bytes, stream);

    const int nbe = (E + CH2 - 1) / CH2;   // 489
    partition_kernel<<<nbe, 256, 0, stream>>>(pre_idx, gcur, part, E, N);
    bucket_sort_kernel<<<NC, 256, 0, stream>>>(
        gcur, part, edgeRec,
        decay, current_factor, gathered_g, v_th, v_reset, normalizer, t_ref,
        exp_dt_k, asc_amps, syn_decay, psc_initial,
        constC, state, N);

    // ---- time loop: ONE kernel per step -------------------------------------
    const int nblk = (N + 255) / 256;    // 196
    for (int t = 0; t < T; ++t) {
        step_kernel<<<nblk, 256, 0, stream>>>(
            ext_input + (size_t)t * n5,
            constC, state,
            ring, scnt, scnt + MD_ + t,
            out + (size_t)t * N,
            edgeRec, weights, edge_basis, post_idx,
            t, n5, N);
    }
}